// Round 2
// baseline (254.934 us; speedup 1.0000x reference)
//
#include <hip/hip_runtime.h>
#include <hip/hip_bf16.h>
#include <stdint.h>

#define KN 32
#define D  128
#define NNODES 20000
#define GRID 2500
#define ITERS 8            // 1 node/iter * 8 iters * 2500 blocks = 20000
#define VOCAB 100000
#define CONV_BLOCKS (VOCAB * D / 2048)   // 6250

typedef __bf16 bf16;
typedef __bf16 bf16x8 __attribute__((ext_vector_type(8)));
typedef float  f32x4  __attribute__((ext_vector_type(4)));

// bf16 e_u LDS layout: 8 chunks/node; chunk c (1024 B, one GL2LDS) holds rows
// {c, c+8, c+16, c+24} (256 B each) + 16 B pad -> 520 bf16 elems per chunk.
// Row r -> elem (r&7)*520 + (r>>3)*128.
#define CHUNK_E 520
#define EU_NODE_E (8 * CHUNK_E)      // 4160 bf16 per node (8320 B)
#define H_STRIDE 136                 // bf16 elems; 68 dw, %32=4

#define GL2LDS(src, dst) __builtin_amdgcn_global_load_lds(                 \
    (const __attribute__((address_space(1))) void*)(src),                  \
    (__attribute__((address_space(3))) void*)(dst), 16, 0, 0)

#define MFMA(a, b, c) __builtin_amdgcn_mfma_f32_16x16x32_bf16((a), (b), (c), 0, 0, 0)

// Raw barrier: LDS-hazard only. Does NOT drain vmcnt, so the prefetch
// global_load_lds queue stays in flight across compute phases.
#define LBAR() do {                                                        \
    asm volatile("s_waitcnt lgkmcnt(0)" ::: "memory");                     \
    __builtin_amdgcn_s_barrier();                                          \
    asm volatile("" ::: "memory");                                         \
    __builtin_amdgcn_sched_barrier(0);                                     \
} while (0)

// ---------------------------------------------------------------------------
// Pack W1 (128x256) and W2 (128x128) fp32 -> bf16 in MFMA B-fragment order.
// B-frag for mfma_f32_16x16x32_bf16: lane holds B[k=quad*8+j][n=lane&15].
// w1p fts 0..3 = e_u half (f in [0,128)), fts 4..7 = self half (f in [128,256)).
// (standalone copy kept for the fallback path)
// ---------------------------------------------------------------------------
__global__ __launch_bounds__(256) void pack_weights_kernel(
    const float* __restrict__ W1, const float* __restrict__ W2,
    bf16* __restrict__ w1p, bf16* __restrict__ w2p)
{
    int t = blockIdx.x * 256 + threadIdx.x;
    if (t < 32768) {
        int j = t & 7, lane = (t >> 3) & 63, kt = (t >> 9) & 7, nt = t >> 12;
        int d = nt * 16 + (lane & 15);
        int f = kt * 32 + ((lane >> 4) << 3) + j;
        w1p[t] = (bf16)W1[d * 256 + f];
    } else if (t < 49152) {
        int u = t - 32768;
        int j = u & 7, lane = (u >> 3) & 63, kt = (u >> 9) & 3, nt = u >> 11;
        int e  = nt * 16 + (lane & 15);
        int dd = kt * 32 + ((lane >> 4) << 3) + j;
        w2p[u] = (bf16)W2[e * 128 + dd];
    }
}

// ---------------------------------------------------------------------------
// Merged prologue: blocks [0, CONV_BLOCKS) convert u2e fp32 -> bf16 table;
// blocks [CONV_BLOCKS, +192) pack W1/W2. One launch.
// ---------------------------------------------------------------------------
__global__ __launch_bounds__(256) void prep_kernel(
    const float* __restrict__ u2e, const float* __restrict__ W1,
    const float* __restrict__ W2,
    bf16* __restrict__ tbl, bf16* __restrict__ w1p, bf16* __restrict__ w2p)
{
    int b = blockIdx.x;
    if (b < CONV_BLOCKS) {
        size_t i = ((size_t)b * 256 + threadIdx.x) * 8;
        float4 a = *(const float4*)(u2e + i);
        float4 c = *(const float4*)(u2e + i + 4);
        bf16x8 v;
        v[0]=(bf16)a.x; v[1]=(bf16)a.y; v[2]=(bf16)a.z; v[3]=(bf16)a.w;
        v[4]=(bf16)c.x; v[5]=(bf16)c.y; v[6]=(bf16)c.z; v[7]=(bf16)c.w;
        *(bf16x8*)(tbl + i) = v;
    } else {
        int t = (b - CONV_BLOCKS) * 256 + threadIdx.x;
        if (t < 32768) {
            int j = t & 7, lane = (t >> 3) & 63, kt = (t >> 9) & 7, nt = t >> 12;
            int d = nt * 16 + (lane & 15);
            int f = kt * 32 + ((lane >> 4) << 3) + j;
            w1p[t] = (bf16)W1[d * 256 + f];
        } else if (t < 49152) {
            int u = t - 32768;
            int j = u & 7, lane = (u >> 3) & 63, kt = (u >> 9) & 3, nt = u >> 11;
            int e  = nt * 16 + (lane & 15);
            int dd = kt * 32 + ((lane >> 4) << 3) + j;
            w2p[u] = (bf16)W2[e * 128 + dd];
        }
    }
}

// ---------------------------------------------------------------------------
// Main kernel: 256 threads = 4 waves, 1 node per iteration, 8 iters/block.
// LDS 27904 B -> >=4 blocks/CU (was 53760 -> 3). Pipelined with a 2-slot eu
// buffer; STAGE(it+1) issued at iter top; counted vmcnt never drains the
// out-store or the prefetch. Self-contribution rows for all 8 nodes computed
// ONCE per block via 8 MFMAs (A rows = the 8 node embeddings), broadcast
// per-iteration with 2 shuffles. STAGE = exactly 4 vmem ops per wave
// (uniform across waves): int2 idx + 2x eu GL2LDS + 1x self GL2LDS.
// vmcnt accounting (in-order retirement): needed = STAGE(it) [4 ops];
// newer = out-store of it-1 [1] + STAGE(it+1) [4] -> vmcnt(5) steady,
// vmcnt(4) at it==0 (no store yet), vmcnt(1) at last iter (no STAGE).
// ---------------------------------------------------------------------------
__global__ __launch_bounds__(256, 4) void graphrec_agg_kernel(
    const int*   __restrict__ nodes,
    const int*   __restrict__ neigh_idx,
    const int*   __restrict__ neigh_len,
    const float* __restrict__ u2e,
    const bf16*  __restrict__ u2e_bf,
    const float* __restrict__ b1,
    const float* __restrict__ b2,
    const float* __restrict__ W3,
    const float* __restrict__ b3,
    const bf16*  __restrict__ w1p,
    const bf16*  __restrict__ w2p,
    float*       __restrict__ out)
{
    __shared__ alignas(16) bf16  eu[2][EU_NODE_E];     // 16640 B (2 slots)
    __shared__ alignas(16) bf16  h1[KN * H_STRIDE];    // 8704 B
    __shared__ float lpart[4 * KN];                    // 512 B
    __shared__ alignas(16) float self_s[2][256];       // 2048 B (2 slots; 128 valid)

    const int t    = threadIdx.x;
    const int lane = t & 63;
    const int wave = t >> 6;
    const int ln15 = lane & 15;
    const int quad = lane >> 4;
    const int nt0  = wave * 2;
    const int r0   = blockIdx.x * ITERS;

    const float bias1_0 = b1[nt0 * 16 + ln15];
    const float bias1_1 = b1[(nt0 + 1) * 16 + ln15];
    const float bias2_0 = b2[nt0 * 16 + ln15];
    const float bias2_1 = b2[(nt0 + 1) * 16 + ln15];
    const float w3_0    = W3[nt0 * 16 + ln15];
    const float w3_1    = W3[(nt0 + 1) * 16 + ln15];
    const float b3v     = b3[0];

    // ---- once-per-block self-contribution: sv[node it][d] for it=0..7 ----
    // A rows = embeddings of the block's 8 nodes (rows 8..15 duplicate 0..7,
    // their C rows are never read). B = W1 self half (fts 4..7 of w1p).
    // C layout: col=lane&15, row=(lane>>4)*4+reg -> sv[it][nt*16+c] lives in
    // lane (it>>2)*16+c, reg it&3.
    f32x4 cs0 = {0.f,0.f,0.f,0.f}, cs1 = cs0;
    {
        int nid = nodes[r0 + (ln15 & 7)];   // per-lane gather of node ids
        #pragma unroll
        for (int kt = 0; kt < 4; ++kt) {
            bf16x8 a  = *(const bf16x8*)(u2e_bf + (size_t)nid * D + kt * 32 + quad * 8);
            bf16x8 b0 = *(const bf16x8*)(w1p + (nt0 * 8 + 4 + kt) * 512 + lane * 8);
            bf16x8 b1f= *(const bf16x8*)(w1p + ((nt0 + 1) * 8 + 4 + kt) * 512 + lane * 8);
            cs0 = MFMA(a, b0, cs0);
            cs1 = MFMA(a, b1f, cs1);
        }
    }

    // resident weight fragments: W1 e_u half + W2 (64 VGPRs)
    bf16x8 w1e[2][4], w2r[2][4];
    #pragma unroll
    for (int nt = 0; nt < 2; ++nt) {
        #pragma unroll
        for (int ft = 0; ft < 4; ++ft)
            w1e[nt][ft] = *(const bf16x8*)(w1p + ((nt0 + nt) * 8 + ft) * 512 + lane * 8);
        #pragma unroll
        for (int kt = 0; kt < 4; ++kt)
            w2r[nt][kt] = *(const bf16x8*)(w2p + ((nt0 + nt) * 4 + kt) * 512 + lane * 8);
    }

    // prefetch: EXACTLY 4 vmem ops per wave, uniform across waves.
    auto STAGE = [&](int jt) {
        const int slot = jt & 1;
        const int n    = r0 + jt;
        const int c0   = wave * 2;            // this wave's 2 chunks
        int2 idx2 = *(const int2*)(neigh_idx + (size_t)n * KN + c0 + (quad << 3));
        bf16* dst = &eu[slot][c0 * CHUNK_E];
        const size_t col = (size_t)(ln15 << 3);
        GL2LDS(u2e_bf + (size_t)idx2.x * D + col, dst);
        GL2LDS(u2e_bf + (size_t)idx2.y * D + col, dst + CHUNK_E);
        int sidx = nodes[n];                  // uniform -> s_load (lgkm)
        GL2LDS(u2e + (size_t)sidx * D + ((size_t)(lane & 31) << 2), &self_s[slot][0]);
    };

    STAGE(0);

    #pragma unroll 1
    for (int it = 0; it < ITERS; ++it) {
        const int n = r0 + it;

        __builtin_amdgcn_sched_barrier(0);
        if (it + 1 < ITERS) STAGE(it + 1);
        __builtin_amdgcn_sched_barrier(0);
        if (it == 0)                 asm volatile("s_waitcnt vmcnt(4)" ::: "memory");
        else if (it + 1 == ITERS)    asm volatile("s_waitcnt vmcnt(1)" ::: "memory");
        else                         asm volatile("s_waitcnt vmcnt(5)" ::: "memory");
        __builtin_amdgcn_s_barrier();
        asm volatile("" ::: "memory");
        __builtin_amdgcn_sched_barrier(0);

        const int len = neigh_len[n];
        const bf16* euN = &eu[it & 1][0];

        // ---- layer 1: [32 x 128] @ [128 x 32slice] + b1 + sv bias ----
        {
            f32x4 c00 = {0.f,0.f,0.f,0.f}, c01 = c00, c10 = c00, c11 = c00;
            const int rb = (ln15 & 7) * CHUNK_E + (ln15 >> 3) * 128;
            #pragma unroll
            for (int ft = 0; ft < 4; ++ft) {
                bf16x8 a0 = *(const bf16x8*)(euN + rb + ft * 32 + quad * 8);
                bf16x8 a1 = *(const bf16x8*)(euN + rb + 256 + ft * 32 + quad * 8);
                c00 = MFMA(a0, w1e[0][ft], c00);
                c01 = MFMA(a0, w1e[1][ft], c01);
                c10 = MFMA(a1, w1e[0][ft], c10);
                c11 = MFMA(a1, w1e[1][ft], c11);
            }
            // sv bias for this node: select reg it&3, shfl from lane (it>>2)*16+ln15
            float sel0 = (it & 2) ? ((it & 1) ? cs0[3] : cs0[2])
                                  : ((it & 1) ? cs0[1] : cs0[0]);
            float sel1 = (it & 2) ? ((it & 1) ? cs1[3] : cs1[2])
                                  : ((it & 1) ? cs1[1] : cs1[0]);
            const int srcl = ((it >> 2) << 4) + ln15;
            const float s0 = __shfl(sel0, srcl);
            const float s1 = __shfl(sel1, srcl);
            #pragma unroll
            for (int r = 0; r < 4; ++r) {      // relu(c + b1 + sv) -> bf16 LDS
                int row = quad * 4 + r;
                h1[row * H_STRIDE + nt0 * 16 + ln15]              = (bf16)fmaxf(c00[r] + bias1_0 + s0, 0.f);
                h1[row * H_STRIDE + (nt0 + 1) * 16 + ln15]        = (bf16)fmaxf(c01[r] + bias1_1 + s1, 0.f);
                h1[(16 + row) * H_STRIDE + nt0 * 16 + ln15]       = (bf16)fmaxf(c10[r] + bias1_0 + s0, 0.f);
                h1[(16 + row) * H_STRIDE + (nt0 + 1) * 16 + ln15] = (bf16)fmaxf(c11[r] + bias1_1 + s1, 0.f);
            }
        }
        LBAR();   // h1 ready (lgkm only; prefetch stays in flight)

        // ---- layer 2 + fused logits ----
        {
            f32x4 d00 = {0.f,0.f,0.f,0.f}, d01 = d00, d10 = d00, d11 = d00;
            #pragma unroll
            for (int kt = 0; kt < 4; ++kt) {
                bf16x8 a0 = *(const bf16x8*)(h1 + ln15 * H_STRIDE + kt * 32 + quad * 8);
                bf16x8 a1 = *(const bf16x8*)(h1 + (16 + ln15) * H_STRIDE + kt * 32 + quad * 8);
                d00 = MFMA(a0, w2r[0][kt], d00);
                d01 = MFMA(a0, w2r[1][kt], d01);
                d10 = MFMA(a1, w2r[0][kt], d10);
                d11 = MFMA(a1, w2r[1][kt], d11);
            }
            #pragma unroll
            for (int r = 0; r < 4; ++r) {   // h2 never materialized
                float p0 = w3_0 * fmaxf(d00[r] + bias2_0, 0.f)
                         + w3_1 * fmaxf(d01[r] + bias2_1, 0.f);
                float p1 = w3_0 * fmaxf(d10[r] + bias2_0, 0.f)
                         + w3_1 * fmaxf(d11[r] + bias2_1, 0.f);
                #pragma unroll
                for (int o = 1; o < 16; o <<= 1) {
                    p0 += __shfl_xor(p0, o);
                    p1 += __shfl_xor(p1, o);
                }
                if (ln15 == 0) {
                    lpart[wave * KN + quad * 4 + r]      = p0;
                    lpart[wave * KN + 16 + quad * 4 + r] = p1;
                }
            }
        }
        LBAR();   // lpart ready

        // ---- softmax + aggregation (all 4 waves on this node) ----
        {
            const int k = lane & 31;
            float lg = lpart[k] + lpart[KN + k] + lpart[2 * KN + k]
                     + lpart[3 * KN + k] + b3v;
            bool act = k < len;
            float l = act ? lg : -1e30f;
            float m = l;
            #pragma unroll
            for (int o = 1; o < 32; o <<= 1) m = fmaxf(m, __shfl_xor(m, o));
            float e = act ? expf(l - m) : 0.f;
            float s = e;
            #pragma unroll
            for (int o = 1; o < 32; o <<= 1) s += __shfl_xor(s, o);
            float att = (s > 0.f) ? (e / s) : 0.f;

            const int cw = wave * 32 + k;     // wave covers 32 of 128 d-cols
            float acc = 0.f;
            #pragma unroll
            for (int k2 = 0; k2 < KN; ++k2) {
                float a  = __shfl(att, k2);   // literal k2 -> v_readlane
                float ev = (float)euN[(k2 & 7) * CHUNK_E + (k2 >> 3) * 128 + cw];
                acc += a * ev;
            }
            float sf = self_s[it & 1][cw];
            if (lane < 32)
                out[(size_t)n * D + cw] = (len > 0) ? 0.5f * (acc + sf) : sf;
        }
        LBAR();   // protect eu/self slot (it+1)&1 before next STAGE overwrite
    }
}

// ---------------------------------------------------------------------------
// Fallback (round-4 kernel, fp32 gather, no sv1) for small ws_size.
// ---------------------------------------------------------------------------
#define FB_CHUNK_DW 260
#define FB_EU_NODE_DW (16 * FB_CHUNK_DW)
#define FB_ITERS 4

__global__ __launch_bounds__(256, 3) void graphrec_agg_fb(
    const int*   __restrict__ nodes,
    const int*   __restrict__ neigh_idx,
    const int*   __restrict__ neigh_len,
    const float* __restrict__ u2e,
    const float* __restrict__ b1,
    const float* __restrict__ b2,
    const float* __restrict__ W3,
    const float* __restrict__ b3,
    const bf16*  __restrict__ w1p,
    const bf16*  __restrict__ w2p,
    float*       __restrict__ out)
{
    __shared__ alignas(16) float eu[2 * FB_EU_NODE_DW];
    __shared__ alignas(16) bf16  h1[2 * KN * H_STRIDE];
    __shared__ alignas(16) float self_f[2 * D];
    __shared__ float lpart[2][4 * KN];
    __shared__ float att_s[2][KN];

    const int t    = threadIdx.x;
    const int lane = t & 63;
    const int wave = t >> 6;
    const int ln15 = lane & 15;
    const int quad = lane >> 4;
    const int nt0  = wave * 2;

    const float bias1_0 = b1[nt0 * 16 + ln15];
    const float bias1_1 = b1[(nt0 + 1) * 16 + ln15];
    const float bias2_0 = b2[nt0 * 16 + ln15];
    const float bias2_1 = b2[(nt0 + 1) * 16 + ln15];
    const float w3_0    = W3[nt0 * 16 + ln15];
    const float w3_1    = W3[(nt0 + 1) * 16 + ln15];
    const float b3v     = b3[0];

    bf16x8 w1r[2][8];
    #pragma unroll
    for (int nt = 0; nt < 2; ++nt)
        #pragma unroll
        for (int ft = 0; ft < 8; ++ft)
            w1r[nt][ft] = *(const bf16x8*)(w1p + ((nt0 + nt) * 8 + ft) * 512 + lane * 8);
    bf16x8 w2r[2][4];
    #pragma unroll
    for (int nt = 0; nt < 2; ++nt)
        #pragma unroll
        for (int kt = 0; kt < 4; ++kt)
            w2r[nt][kt] = *(const bf16x8*)(w2p + ((nt0 + nt) * 4 + kt) * 512 + lane * 8);

    #pragma unroll 1
    for (int it = 0; it < FB_ITERS; ++it) {
        const int nA   = blockIdx.x * 8 + it * 2;
        const int lenA = neigh_len[nA];
        const int lenB = neigh_len[nA + 1];
        {
            const int half = lane >> 5;
            const int colb = (lane & 31) << 4;
            #pragma unroll
            for (int nd = 0; nd < 2; ++nd) {
                #pragma unroll
                for (int j = 0; j < 4; ++j) {
                    int chunk = wave * 4 + j;
                    int idx = neigh_idx[(nA + nd) * KN + chunk + (half << 4)];
                    const char* src = (const char*)(u2e + (size_t)idx * D) + colb;
                    GL2LDS(src, eu + nd * FB_EU_NODE_DW + chunk * FB_CHUNK_DW);
                }
            }
            if (wave == 0) {
                int sidx = nodes[nA + half];
                const char* src = (const char*)(u2e + (size_t)sidx * D) + colb;
                GL2LDS(src, self_f);
            }
        }
        __syncthreads();
        #pragma unroll 1
        for (int nd = 0; nd < 2; ++nd) {
            const float* euN = eu + nd * FB_EU_NODE_DW;
            const float* sfN = self_f + nd * D;
            bf16* h1N = h1 + nd * KN * H_STRIDE;
            f32x4 c00 = {0.f,0.f,0.f,0.f}, c01 = c00, c10 = c00, c11 = c00;
            const int r0 = ln15 * FB_CHUNK_DW;
            #pragma unroll
            for (int ft = 0; ft < 4; ++ft) {
                int off = ft * 32 + quad * 8;
                f32x4 u0 = *(const f32x4*)(euN + r0 + off);
                f32x4 u1 = *(const f32x4*)(euN + r0 + off + 4);
                f32x4 v0 = *(const f32x4*)(euN + r0 + 128 + off);
                f32x4 v1 = *(const f32x4*)(euN + r0 + 128 + off + 4);
                bf16x8 a0, a1;
                #pragma unroll
                for (int e = 0; e < 4; ++e) {
                    a0[e] = (bf16)u0[e]; a0[4 + e] = (bf16)u1[e];
                    a1[e] = (bf16)v0[e]; a1[4 + e] = (bf16)v1[e];
                }
                c00 = MFMA(a0, w1r[0][ft], c00);
                c01 = MFMA(a0, w1r[1][ft], c01);
                c10 = MFMA(a1, w1r[0][ft], c10);
                c11 = MFMA(a1, w1r[1][ft], c11);
            }
            #pragma unroll
            for (int ft = 4; ft < 8; ++ft) {
                int off = (ft - 4) * 32 + quad * 8;
                f32x4 u0 = *(const f32x4*)(sfN + off);
                f32x4 u1 = *(const f32x4*)(sfN + off + 4);
                bf16x8 a;
                #pragma unroll
                for (int e = 0; e < 4; ++e) { a[e] = (bf16)u0[e]; a[4 + e] = (bf16)u1[e]; }
                c00 = MFMA(a, w1r[0][ft], c00);
                c01 = MFMA(a, w1r[1][ft], c01);
                c10 = MFMA(a, w1r[0][ft], c10);
                c11 = MFMA(a, w1r[1][ft], c11);
            }
            #pragma unroll
            for (int r = 0; r < 4; ++r) {
                int row = quad * 4 + r;
                h1N[row * H_STRIDE + nt0 * 16 + ln15]              = (bf16)fmaxf(c00[r] + bias1_0, 0.f);
                h1N[row * H_STRIDE + (nt0 + 1) * 16 + ln15]        = (bf16)fmaxf(c01[r] + bias1_1, 0.f);
                h1N[(16 + row) * H_STRIDE + nt0 * 16 + ln15]       = (bf16)fmaxf(c10[r] + bias1_0, 0.f);
                h1N[(16 + row) * H_STRIDE + (nt0 + 1) * 16 + ln15] = (bf16)fmaxf(c11[r] + bias1_1, 0.f);
            }
        }
        __syncthreads();
        #pragma unroll 1
        for (int nd = 0; nd < 2; ++nd) {
            const bf16* h1N = h1 + nd * KN * H_STRIDE;
            f32x4 d00 = {0.f,0.f,0.f,0.f}, d01 = d00, d10 = d00, d11 = d00;
            #pragma unroll
            for (int kt = 0; kt < 4; ++kt) {
                bf16x8 a0 = *(const bf16x8*)(h1N + ln15 * H_STRIDE + kt * 32 + quad * 8);
                bf16x8 a1 = *(const bf16x8*)(h1N + (16 + ln15) * H_STRIDE + kt * 32 + quad * 8);
                d00 = MFMA(a0, w2r[0][kt], d00);
                d01 = MFMA(a0, w2r[1][kt], d01);
                d10 = MFMA(a1, w2r[0][kt], d10);
                d11 = MFMA(a1, w2r[1][kt], d11);
            }
            #pragma unroll
            for (int r = 0; r < 4; ++r) {
                float p0 = w3_0 * fmaxf(d00[r] + bias2_0, 0.f)
                         + w3_1 * fmaxf(d01[r] + bias2_1, 0.f);
                float p1 = w3_0 * fmaxf(d10[r] + bias2_0, 0.f)
                         + w3_1 * fmaxf(d11[r] + bias2_1, 0.f);
                #pragma unroll
                for (int o = 1; o < 16; o <<= 1) {
                    p0 += __shfl_xor(p0, o);
                    p1 += __shfl_xor(p1, o);
                }
                if (ln15 == 0) {
                    lpart[nd][wave * KN + quad * 4 + r]      = p0;
                    lpart[nd][wave * KN + 16 + quad * 4 + r] = p1;
                }
            }
        }
        __syncthreads();
        if (wave < 2) {
            int nd = wave, k = lane & 31;
            float lg = lpart[nd][k] + lpart[nd][KN + k] + lpart[nd][2 * KN + k]
                     + lpart[nd][3 * KN + k] + b3v;
            int len = nd ? lenB : lenA;
            bool act = (lane < 32) && (k < len);
            float l = act ? lg : -1e30f;
            float m = l;
            #pragma unroll
            for (int o = 1; o < 32; o <<= 1) m = fmaxf(m, __shfl_xor(m, o));
            float e = act ? expf(l - m) : 0.f;
            float s = e;
            #pragma unroll
            for (int o = 1; o < 32; o <<= 1) s += __shfl_xor(s, o);
            if (lane < 32) att_s[nd][k] = (s > 0.f) ? (e / s) : 0.f;
        }
        __syncthreads();
        {
            int nd = t >> 7, d = t & 127;
            const float* euN = eu + nd * FB_EU_NODE_DW;
            float acc = 0.f;
            #pragma unroll
            for (int k = 0; k < KN; ++k)
                acc += att_s[nd][k] * euN[(k & 15) * FB_CHUNK_DW + ((k >> 4) << 7) + d];
            float sf = self_f[nd * D + d];
            int len = nd ? lenB : lenA;
            out[(size_t)(nA + nd) * D + d] = (len > 0) ? 0.5f * (acc + sf) : sf;
        }
        __syncthreads();
    }
}

extern "C" void kernel_launch(void* const* d_in, const int* in_sizes, int n_in,
                              void* d_out, int out_size, void* d_ws, size_t ws_size,
                              hipStream_t stream) {
    const int*   nodes     = (const int*)d_in[0];
    const int*   neigh_idx = (const int*)d_in[1];
    const int*   neigh_len = (const int*)d_in[2];
    const float* u2e       = (const float*)d_in[3];
    const float* W1        = (const float*)d_in[4];
    const float* b1        = (const float*)d_in[5];
    const float* W2        = (const float*)d_in[6];
    const float* b2        = (const float*)d_in[7];
    const float* W3        = (const float*)d_in[8];
    const float* b3        = (const float*)d_in[9];
    float* out = (float*)d_out;

    bf16*  w1p    = (bf16*)d_ws;                                  // 65536 B
    bf16*  w2p    = w1p + 32768;                                  // 32768 B
    bf16*  u2e_bf = (bf16*)((char*)d_ws + 98304);                 // 25.6 MB
    const size_t need = 98304ull + (size_t)VOCAB * D * 2;

    if (ws_size >= need) {
        prep_kernel<<<CONV_BLOCKS + 192, 256, 0, stream>>>(u2e, W1, W2,
                                                           u2e_bf, w1p, w2p);
        graphrec_agg_kernel<<<GRID, 256, 0, stream>>>(nodes, neigh_idx, neigh_len,
                                                      u2e, u2e_bf, b1, b2,
                                                      W3, b3, w1p, w2p, out);
    } else {
        pack_weights_kernel<<<192, 256, 0, stream>>>(W1, W2, w1p, w2p);
        graphrec_agg_fb<<<GRID, 256, 0, stream>>>(nodes, neigh_idx, neigh_len, u2e,
                                                  b1, b2, W3, b3, w1p, w2p, out);
    }
}

// Round 4
// 216.078 us; speedup vs baseline: 1.1798x; 1.1798x over previous
//
#include <hip/hip_runtime.h>
#include <hip/hip_bf16.h>
#include <stdint.h>

#define KN 32
#define D  128
#define NNODES 20000
#define GRID 2500
#define ITERS 4            // 2 nodes/iter * 4 iters * 2500 blocks = 20000
#define VOCAB 100000
#define CONV_BLOCKS (VOCAB * D / 2048)   // 6250

typedef __bf16 bf16;
typedef __bf16 bf16x8 __attribute__((ext_vector_type(8)));
typedef float  f32x4  __attribute__((ext_vector_type(4)));

// bf16 e_u LDS layout: 8 chunks/node; chunk c (1024 B, one GL2LDS) holds rows
// {c, c+8, c+16, c+24} (256 B each) + 16 B pad -> 520 bf16 elems per chunk.
// Row r -> elem (r&7)*520 + (r>>3)*128.
#define CHUNK_E 520
#define EU_NODE_E (8 * CHUNK_E)      // 4160 bf16 per node
#define H_STRIDE 136                 // bf16 elems; 68 dw, %32=4

#define GL2LDS(src, dst) __builtin_amdgcn_global_load_lds(                 \
    (const __attribute__((address_space(1))) void*)(src),                  \
    (__attribute__((address_space(3))) void*)(dst), 16, 0, 0)

#define MFMA(a, b, c) __builtin_amdgcn_mfma_f32_16x16x32_bf16((a), (b), (c), 0, 0, 0)

// ---------------------------------------------------------------------------
// Pack W1 (128x256) and W2 (128x128) fp32 -> bf16 in MFMA B-fragment order.
// B-frag for mfma_f32_16x16x32_bf16: lane holds B[k=quad*8+j][n=lane&15].
// w1p fts 0..3 = e_u half (f in [0,128)), fts 4..7 = self half (f in [128,256)).
// (standalone copy kept for the fallback path)
// ---------------------------------------------------------------------------
__global__ __launch_bounds__(256) void pack_weights_kernel(
    const float* __restrict__ W1, const float* __restrict__ W2,
    bf16* __restrict__ w1p, bf16* __restrict__ w2p)
{
    int t = blockIdx.x * 256 + threadIdx.x;
    if (t < 32768) {
        int j = t & 7, lane = (t >> 3) & 63, kt = (t >> 9) & 7, nt = t >> 12;
        int d = nt * 16 + (lane & 15);
        int f = kt * 32 + ((lane >> 4) << 3) + j;
        w1p[t] = (bf16)W1[d * 256 + f];
    } else if (t < 49152) {
        int u = t - 32768;
        int j = u & 7, lane = (u >> 3) & 63, kt = (u >> 9) & 3, nt = u >> 11;
        int e  = nt * 16 + (lane & 15);
        int dd = kt * 32 + ((lane >> 4) << 3) + j;
        w2p[u] = (bf16)W2[e * 128 + dd];
    }
}

// ---------------------------------------------------------------------------
// Merged prologue: blocks [0, CONV_BLOCKS) convert u2e fp32 -> bf16 table;
// blocks [CONV_BLOCKS, +192) pack W1/W2. One launch.
// ---------------------------------------------------------------------------
__global__ __launch_bounds__(256) void prep_kernel(
    const float* __restrict__ u2e, const float* __restrict__ W1,
    const float* __restrict__ W2,
    bf16* __restrict__ tbl, bf16* __restrict__ w1p, bf16* __restrict__ w2p)
{
    int b = blockIdx.x;
    if (b < CONV_BLOCKS) {
        size_t i = ((size_t)b * 256 + threadIdx.x) * 8;
        float4 a = *(const float4*)(u2e + i);
        float4 c = *(const float4*)(u2e + i + 4);
        bf16x8 v;
        v[0]=(bf16)a.x; v[1]=(bf16)a.y; v[2]=(bf16)a.z; v[3]=(bf16)a.w;
        v[4]=(bf16)c.x; v[5]=(bf16)c.y; v[6]=(bf16)c.z; v[7]=(bf16)c.w;
        *(bf16x8*)(tbl + i) = v;
    } else {
        int t = (b - CONV_BLOCKS) * 256 + threadIdx.x;
        if (t < 32768) {
            int j = t & 7, lane = (t >> 3) & 63, kt = (t >> 9) & 7, nt = t >> 12;
            int d = nt * 16 + (lane & 15);
            int f = kt * 32 + ((lane >> 4) << 3) + j;
            w1p[t] = (bf16)W1[d * 256 + f];
        } else if (t < 49152) {
            int u = t - 32768;
            int j = u & 7, lane = (u >> 3) & 63, kt = (u >> 9) & 3, nt = u >> 11;
            int e  = nt * 16 + (lane & 15);
            int dd = kt * 32 + ((lane >> 4) << 3) + j;
            w2p[u] = (bf16)W2[e * 128 + dd];
        }
    }
}

// ---------------------------------------------------------------------------
// Main kernel: round-0 structure (best measured: 111.7 us). 256 threads =
// 4 waves, 2 nodes/iter, 4 iters/block, plain __syncthreads (cross-block TLP
// at 4 blocks/CU hides gather latency; pipelining attempts R1/R2 both lost).
// Deltas vs round 0:
//  - sv1 prologue kernel REMOVED: the layer-1 self half for all 8 of this
//    block's nodes is computed once per block with 8 MFMAs (A rows 0..7 =
//    node embeddings, B = W1 self-half frags), kept in cs0/cs1 (8 VGPRs),
//    broadcast per-iteration with 4 shuffles. Kills sv1t's 10.24 MB write
//    + 10.24 MB read + per-iter scalar-load latency.
//  - prep merged into one launch (round-1 keeper).
// LDS 36096 B -> 4 blocks/CU, same as round 0.
// ---------------------------------------------------------------------------
__global__ __launch_bounds__(256, 4) void graphrec_agg_kernel(
    const int*   __restrict__ nodes,
    const int*   __restrict__ neigh_idx,
    const int*   __restrict__ neigh_len,
    const float* __restrict__ u2e,
    const bf16*  __restrict__ u2e_bf,
    const float* __restrict__ b1,
    const float* __restrict__ b2,
    const float* __restrict__ W3,
    const float* __restrict__ b3,
    const bf16*  __restrict__ w1p,
    const bf16*  __restrict__ w2p,
    float*       __restrict__ out)
{
    __shared__ alignas(16) bf16  eu[2 * EU_NODE_E];     // 16640 B
    __shared__ alignas(16) float self_f[2 * D];         // 1024 B (A||B)
    __shared__ alignas(16) bf16  h1[2 * KN * H_STRIDE]; // 17408 B
    __shared__ float lpart[2][4 * KN];                  // 1024 B

    const int t    = threadIdx.x;
    const int lane = t & 63;
    const int wave = t >> 6;
    const int ln15 = lane & 15;
    const int quad = lane >> 4;
    const int nt0  = wave * 2;

    const float bias1_0 = b1[nt0 * 16 + ln15];
    const float bias1_1 = b1[(nt0 + 1) * 16 + ln15];
    const float bias2_0 = b2[nt0 * 16 + ln15];
    const float bias2_1 = b2[(nt0 + 1) * 16 + ln15];
    const float w3_0    = W3[nt0 * 16 + ln15];
    const float w3_1    = W3[(nt0 + 1) * 16 + ln15];
    const float b3v     = b3[0];

    // ---- once-per-block self-contribution (replaces sv1 kernel) ----
    // A rows 0..7 = embeddings of this block's 8 nodes (rows 8..15 duplicate,
    // never read). B = W1 self half (fts 4..7). C layout: col=lane&15,
    // row=(lane>>4)*4+reg -> node j lives in lanes (j>>2)*16+c, reg j&3.
    f32x4 cs0 = {0.f,0.f,0.f,0.f}, cs1 = cs0;
    {
        int nid = nodes[blockIdx.x * 8 + (ln15 & 7)];
        #pragma unroll
        for (int kt = 0; kt < 4; ++kt) {
            bf16x8 a   = *(const bf16x8*)(u2e_bf + (size_t)nid * D + kt * 32 + quad * 8);
            bf16x8 bb0 = *(const bf16x8*)(w1p + (nt0 * 8 + 4 + kt) * 512 + lane * 8);
            bf16x8 bb1 = *(const bf16x8*)(w1p + ((nt0 + 1) * 8 + 4 + kt) * 512 + lane * 8);
            cs0 = MFMA(a, bb0, cs0);
            cs1 = MFMA(a, bb1, cs1);
        }
    }

    // resident weight fragments: 64 VGPRs (W1 e_u half + W2)
    bf16x8 w1r[2][4];
    #pragma unroll
    for (int nt = 0; nt < 2; ++nt)
        #pragma unroll
        for (int ft = 0; ft < 4; ++ft)
            w1r[nt][ft] = *(const bf16x8*)(w1p + ((nt0 + nt) * 8 + ft) * 512 + lane * 8);
    bf16x8 w2r[2][4];
    #pragma unroll
    for (int nt = 0; nt < 2; ++nt)
        #pragma unroll
        for (int kt = 0; kt < 4; ++kt)
            w2r[nt][kt] = *(const bf16x8*)(w2p + ((nt0 + nt) * 4 + kt) * 512 + lane * 8);

    #pragma unroll 1
    for (int it = 0; it < ITERS; ++it) {
        const int nA   = blockIdx.x * 8 + it * 2;
        const int lenA = neigh_len[nA];
        const int lenB = neigh_len[nA + 1];

        // ---- async gather: bf16 e_u direct to LDS (4 chunks/wave) ----
        {
            const int gnd = wave >> 1;            // node this wave stages
            const int cb  = (wave & 1) * 4;       // first of its 4 chunks
            #pragma unroll
            for (int j = 0; j < 4; ++j) {
                int chunk = cb + j;
                int idx = neigh_idx[(nA + gnd) * KN + chunk + ((lane >> 4) << 3)];
                GL2LDS(u2e_bf + (size_t)idx * D + ((lane & 15) << 3),
                       eu + gnd * EU_NODE_E + chunk * CHUNK_E);
            }
            if (wave == 0) {                      // selfA||selfB fp32, ONE instr
                int sidx = nodes[nA + (lane >> 5)];
                GL2LDS(u2e + (size_t)sidx * D + ((lane & 31) << 2), self_f);
            }
        }
        __syncthreads();   // barrier 1: gather resident

        // sv bias broadcast for nodes 2it (A) and 2it+1 (B):
        // node j = 2it+nd -> reg 2*(it&1)+nd, source lane (it>>1)*16+ln15.
        const bool hi = (it & 1);
        const float selA0 = hi ? cs0[2] : cs0[0];
        const float selB0 = hi ? cs0[3] : cs0[1];
        const float selA1 = hi ? cs1[2] : cs1[0];
        const float selB1 = hi ? cs1[3] : cs1[1];
        const int   srcl  = ((it >> 1) << 4) + ln15;
        const float svA0 = __shfl(selA0, srcl);
        const float svB0 = __shfl(selB0, srcl);
        const float svA1 = __shfl(selA1, srcl);
        const float svB1 = __shfl(selB1, srcl);

        // ---- layer 1, both nodes: [32 x 128] @ [128 x 128] + sv bias ----
        #pragma unroll 1
        for (int nd = 0; nd < 2; ++nd) {
            const bf16* euN = eu + nd * EU_NODE_E;
            bf16* h1N = h1 + nd * KN * H_STRIDE;

            f32x4 c00 = {0.f,0.f,0.f,0.f}, c01 = c00, c10 = c00, c11 = c00;
            const int rb = (ln15 & 7) * CHUNK_E + (ln15 >> 3) * 128;
            #pragma unroll
            for (int ft = 0; ft < 4; ++ft) {
                bf16x8 a0 = *(const bf16x8*)(euN + rb + ft * 32 + quad * 8);
                bf16x8 a1 = *(const bf16x8*)(euN + rb + 256 + ft * 32 + quad * 8);
                c00 = MFMA(a0, w1r[0][ft], c00);
                c01 = MFMA(a0, w1r[1][ft], c01);
                c10 = MFMA(a1, w1r[0][ft], c10);
                c11 = MFMA(a1, w1r[1][ft], c11);
            }
            const float s0 = nd ? svB0 : svA0;
            const float s1 = nd ? svB1 : svA1;
            #pragma unroll
            for (int r = 0; r < 4; ++r) {      // relu(c + b1 + sv) -> bf16 LDS
                int row = quad * 4 + r;
                h1N[row * H_STRIDE + nt0 * 16 + ln15]              = (bf16)fmaxf(c00[r] + bias1_0 + s0, 0.f);
                h1N[row * H_STRIDE + (nt0 + 1) * 16 + ln15]        = (bf16)fmaxf(c01[r] + bias1_1 + s1, 0.f);
                h1N[(16 + row) * H_STRIDE + nt0 * 16 + ln15]       = (bf16)fmaxf(c10[r] + bias1_0 + s0, 0.f);
                h1N[(16 + row) * H_STRIDE + (nt0 + 1) * 16 + ln15] = (bf16)fmaxf(c11[r] + bias1_1 + s1, 0.f);
            }
        }
        __syncthreads();   // barrier 2

        // ---- layer 2 + fused logits, both nodes ----
        #pragma unroll 1
        for (int nd = 0; nd < 2; ++nd) {
            const bf16* h1N = h1 + nd * KN * H_STRIDE;
            f32x4 d00 = {0.f,0.f,0.f,0.f}, d01 = d00, d10 = d00, d11 = d00;
            #pragma unroll
            for (int kt = 0; kt < 4; ++kt) {
                bf16x8 a0 = *(const bf16x8*)(h1N + ln15 * H_STRIDE + kt * 32 + quad * 8);
                bf16x8 a1 = *(const bf16x8*)(h1N + (16 + ln15) * H_STRIDE + kt * 32 + quad * 8);
                d00 = MFMA(a0, w2r[0][kt], d00);
                d01 = MFMA(a0, w2r[1][kt], d01);
                d10 = MFMA(a1, w2r[0][kt], d10);
                d11 = MFMA(a1, w2r[1][kt], d11);
            }
            #pragma unroll
            for (int r = 0; r < 4; ++r) {   // h2 never materialized
                float p0 = w3_0 * fmaxf(d00[r] + bias2_0, 0.f)
                         + w3_1 * fmaxf(d01[r] + bias2_1, 0.f);
                float p1 = w3_0 * fmaxf(d10[r] + bias2_0, 0.f)
                         + w3_1 * fmaxf(d11[r] + bias2_1, 0.f);
                #pragma unroll
                for (int o = 1; o < 16; o <<= 1) {
                    p0 += __shfl_xor(p0, o);
                    p1 += __shfl_xor(p1, o);
                }
                if (ln15 == 0) {
                    lpart[nd][wave * KN + quad * 4 + r]      = p0;
                    lpart[nd][wave * KN + 16 + quad * 4 + r] = p1;
                }
            }
        }
        __syncthreads();   // barrier 3

        // ---- per-wave softmax + aggregation (wave w: node w>>1, cols (w&1)*64..) ----
        {
            const int nd = wave >> 1;
            const int k  = lane & 31;
            float lg = lpart[nd][k] + lpart[nd][KN + k] + lpart[nd][2 * KN + k]
                     + lpart[nd][3 * KN + k] + b3v;
            const int len = nd ? lenB : lenA;
            bool act = k < len;
            float l = act ? lg : -1e30f;
            float m = l;
            #pragma unroll
            for (int o = 1; o < 32; o <<= 1) m = fmaxf(m, __shfl_xor(m, o));
            float e = act ? expf(l - m) : 0.f;
            float s = e;
            #pragma unroll
            for (int o = 1; o < 32; o <<= 1) s += __shfl_xor(s, o);
            float att = (s > 0.f) ? (e / s) : 0.f;

            const int d = ((wave & 1) << 6) + lane;   // wave covers 64 of 128 cols
            const bf16* euN = eu + nd * EU_NODE_E;
            float acc = 0.f;
            #pragma unroll
            for (int k2 = 0; k2 < KN; ++k2) {
                float a  = __shfl(att, k2);
                float ev = (float)euN[(k2 & 7) * CHUNK_E + (k2 >> 3) * 128 + (d & 127)];
                acc += a * ev;
            }
            float sf = self_f[nd * D + (d & 127)];
            out[(size_t)(nA + nd) * D + (d & 127)] = (len > 0) ? 0.5f * (acc + sf) : sf;
        }
        __syncthreads();   // barrier 4: protect LDS for next iteration
    }
}

// ---------------------------------------------------------------------------
// Fallback (round-4 kernel, fp32 gather, no sv1) for small ws_size.
// ---------------------------------------------------------------------------
#define FB_CHUNK_DW 260
#define FB_EU_NODE_DW (16 * FB_CHUNK_DW)

__global__ __launch_bounds__(256, 3) void graphrec_agg_fb(
    const int*   __restrict__ nodes,
    const int*   __restrict__ neigh_idx,
    const int*   __restrict__ neigh_len,
    const float* __restrict__ u2e,
    const float* __restrict__ b1,
    const float* __restrict__ b2,
    const float* __restrict__ W3,
    const float* __restrict__ b3,
    const bf16*  __restrict__ w1p,
    const bf16*  __restrict__ w2p,
    float*       __restrict__ out)
{
    __shared__ alignas(16) float eu[2 * FB_EU_NODE_DW];
    __shared__ alignas(16) bf16  h1[2 * KN * H_STRIDE];
    __shared__ alignas(16) float self_f[2 * D];
    __shared__ float lpart[2][4 * KN];
    __shared__ float att_s[2][KN];

    const int t    = threadIdx.x;
    const int lane = t & 63;
    const int wave = t >> 6;
    const int ln15 = lane & 15;
    const int quad = lane >> 4;
    const int nt0  = wave * 2;

    const float bias1_0 = b1[nt0 * 16 + ln15];
    const float bias1_1 = b1[(nt0 + 1) * 16 + ln15];
    const float bias2_0 = b2[nt0 * 16 + ln15];
    const float bias2_1 = b2[(nt0 + 1) * 16 + ln15];
    const float w3_0    = W3[nt0 * 16 + ln15];
    const float w3_1    = W3[(nt0 + 1) * 16 + ln15];
    const float b3v     = b3[0];

    bf16x8 w1r[2][8];
    #pragma unroll
    for (int nt = 0; nt < 2; ++nt)
        #pragma unroll
        for (int ft = 0; ft < 8; ++ft)
            w1r[nt][ft] = *(const bf16x8*)(w1p + ((nt0 + nt) * 8 + ft) * 512 + lane * 8);
    bf16x8 w2r[2][4];
    #pragma unroll
    for (int nt = 0; nt < 2; ++nt)
        #pragma unroll
        for (int kt = 0; kt < 4; ++kt)
            w2r[nt][kt] = *(const bf16x8*)(w2p + ((nt0 + nt) * 4 + kt) * 512 + lane * 8);

    #pragma unroll 1
    for (int it = 0; it < 4; ++it) {
        const int nA   = blockIdx.x * 8 + it * 2;
        const int lenA = neigh_len[nA];
        const int lenB = neigh_len[nA + 1];
        {
            const int half = lane >> 5;
            const int colb = (lane & 31) << 4;
            #pragma unroll
            for (int nd = 0; nd < 2; ++nd) {
                #pragma unroll
                for (int j = 0; j < 4; ++j) {
                    int chunk = wave * 4 + j;
                    int idx = neigh_idx[(nA + nd) * KN + chunk + (half << 4)];
                    const char* src = (const char*)(u2e + (size_t)idx * D) + colb;
                    GL2LDS(src, eu + nd * FB_EU_NODE_DW + chunk * FB_CHUNK_DW);
                }
            }
            if (wave == 0) {
                int sidx = nodes[nA + half];
                const char* src = (const char*)(u2e + (size_t)sidx * D) + colb;
                GL2LDS(src, self_f);
            }
        }
        __syncthreads();
        #pragma unroll 1
        for (int nd = 0; nd < 2; ++nd) {
            const float* euN = eu + nd * FB_EU_NODE_DW;
            const float* sfN = self_f + nd * D;
            bf16* h1N = h1 + nd * KN * H_STRIDE;
            f32x4 c00 = {0.f,0.f,0.f,0.f}, c01 = c00, c10 = c00, c11 = c00;
            const int r0 = ln15 * FB_CHUNK_DW;
            #pragma unroll
            for (int ft = 0; ft < 4; ++ft) {
                int off = ft * 32 + quad * 8;
                f32x4 u0 = *(const f32x4*)(euN + r0 + off);
                f32x4 u1 = *(const f32x4*)(euN + r0 + off + 4);
                f32x4 v0 = *(const f32x4*)(euN + r0 + 128 + off);
                f32x4 v1 = *(const f32x4*)(euN + r0 + 128 + off + 4);
                bf16x8 a0, a1;
                #pragma unroll
                for (int e = 0; e < 4; ++e) {
                    a0[e] = (bf16)u0[e]; a0[4 + e] = (bf16)u1[e];
                    a1[e] = (bf16)v0[e]; a1[4 + e] = (bf16)v1[e];
                }
                c00 = MFMA(a0, w1r[0][ft], c00);
                c01 = MFMA(a0, w1r[1][ft], c01);
                c10 = MFMA(a1, w1r[0][ft], c10);
                c11 = MFMA(a1, w1r[1][ft], c11);
            }
            #pragma unroll
            for (int ft = 4; ft < 8; ++ft) {
                int off = (ft - 4) * 32 + quad * 8;
                f32x4 u0 = *(const f32x4*)(sfN + off);
                f32x4 u1 = *(const f32x4*)(sfN + off + 4);
                bf16x8 a;
                #pragma unroll
                for (int e = 0; e < 4; ++e) { a[e] = (bf16)u0[e]; a[4 + e] = (bf16)u1[e]; }
                c00 = MFMA(a, w1r[0][ft], c00);
                c01 = MFMA(a, w1r[1][ft], c01);
                c10 = MFMA(a, w1r[0][ft], c10);
                c11 = MFMA(a, w1r[1][ft], c11);
            }
            #pragma unroll
            for (int r = 0; r < 4; ++r) {
                int row = quad * 4 + r;
                h1N[row * H_STRIDE + nt0 * 16 + ln15]              = (bf16)fmaxf(c00[r] + bias1_0, 0.f);
                h1N[row * H_STRIDE + (nt0 + 1) * 16 + ln15]        = (bf16)fmaxf(c01[r] + bias1_1, 0.f);
                h1N[(16 + row) * H_STRIDE + nt0 * 16 + ln15]       = (bf16)fmaxf(c10[r] + bias1_0, 0.f);
                h1N[(16 + row) * H_STRIDE + (nt0 + 1) * 16 + ln15] = (bf16)fmaxf(c11[r] + bias1_1, 0.f);
            }
        }
        __syncthreads();
        #pragma unroll 1
        for (int nd = 0; nd < 2; ++nd) {
            const bf16* h1N = h1 + nd * KN * H_STRIDE;
            f32x4 d00 = {0.f,0.f,0.f,0.f}, d01 = d00, d10 = d00, d11 = d00;
            #pragma unroll
            for (int kt = 0; kt < 4; ++kt) {
                bf16x8 a0 = *(const bf16x8*)(h1N + ln15 * H_STRIDE + kt * 32 + quad * 8);
                bf16x8 a1 = *(const bf16x8*)(h1N + (16 + ln15) * H_STRIDE + kt * 32 + quad * 8);
                d00 = MFMA(a0, w2r[0][kt], d00);
                d01 = MFMA(a0, w2r[1][kt], d01);
                d10 = MFMA(a1, w2r[0][kt], d10);
                d11 = MFMA(a1, w2r[1][kt], d11);
            }
            #pragma unroll
            for (int r = 0; r < 4; ++r) {
                float p0 = w3_0 * fmaxf(d00[r] + bias2_0, 0.f)
                         + w3_1 * fmaxf(d01[r] + bias2_1, 0.f);
                float p1 = w3_0 * fmaxf(d10[r] + bias2_0, 0.f)
                         + w3_1 * fmaxf(d11[r] + bias2_1, 0.f);
                #pragma unroll
                for (int o = 1; o < 16; o <<= 1) {
                    p0 += __shfl_xor(p0, o);
                    p1 += __shfl_xor(p1, o);
                }
                if (ln15 == 0) {
                    lpart[nd][wave * KN + quad * 4 + r]      = p0;
                    lpart[nd][wave * KN + 16 + quad * 4 + r] = p1;
                }
            }
        }
        __syncthreads();
        if (wave < 2) {
            int nd = wave, k = lane & 31;
            float lg = lpart[nd][k] + lpart[nd][KN + k] + lpart[nd][2 * KN + k]
                     + lpart[nd][3 * KN + k] + b3v;
            int len = nd ? lenB : lenA;
            bool act = (lane < 32) && (k < len);
            float l = act ? lg : -1e30f;
            float m = l;
            #pragma unroll
            for (int o = 1; o < 32; o <<= 1) m = fmaxf(m, __shfl_xor(m, o));
            float e = act ? expf(l - m) : 0.f;
            float s = e;
            #pragma unroll
            for (int o = 1; o < 32; o <<= 1) s += __shfl_xor(s, o);
            if (lane < 32) att_s[nd][k] = (s > 0.f) ? (e / s) : 0.f;
        }
        __syncthreads();
        {
            int nd = t >> 7, d = t & 127;
            const float* euN = eu + nd * FB_EU_NODE_DW;
            float acc = 0.f;
            #pragma unroll
            for (int k = 0; k < KN; ++k)
                acc += att_s[nd][k] * euN[(k & 15) * FB_CHUNK_DW + ((k >> 4) << 7) + d];
            float sf = self_f[nd * D + d];
            int len = nd ? lenB : lenA;
            out[(size_t)(nA + nd) * D + d] = (len > 0) ? 0.5f * (acc + sf) : sf;
        }
        __syncthreads();
    }
}

extern "C" void kernel_launch(void* const* d_in, const int* in_sizes, int n_in,
                              void* d_out, int out_size, void* d_ws, size_t ws_size,
                              hipStream_t stream) {
    const int*   nodes     = (const int*)d_in[0];
    const int*   neigh_idx = (const int*)d_in[1];
    const int*   neigh_len = (const int*)d_in[2];
    const float* u2e       = (const float*)d_in[3];
    const float* W1        = (const float*)d_in[4];
    const float* b1        = (const float*)d_in[5];
    const float* W2        = (const float*)d_in[6];
    const float* b2        = (const float*)d_in[7];
    const float* W3        = (const float*)d_in[8];
    const float* b3        = (const float*)d_in[9];
    float* out = (float*)d_out;

    bf16*  w1p    = (bf16*)d_ws;                                  // 65536 B
    bf16*  w2p    = w1p + 32768;                                  // 32768 B
    bf16*  u2e_bf = (bf16*)((char*)d_ws + 98304);                 // 25.6 MB
    const size_t need = 98304ull + (size_t)VOCAB * D * 2;

    if (ws_size >= need) {
        prep_kernel<<<CONV_BLOCKS + 192, 256, 0, stream>>>(u2e, W1, W2,
                                                           u2e_bf, w1p, w2p);
        graphrec_agg_kernel<<<GRID, 256, 0, stream>>>(nodes, neigh_idx, neigh_len,
                                                      u2e, u2e_bf, b1, b2,
                                                      W3, b3, w1p, w2p, out);
    } else {
        pack_weights_kernel<<<192, 256, 0, stream>>>(W1, W2, w1p, w2p);
        graphrec_agg_fb<<<GRID, 256, 0, stream>>>(nodes, neigh_idx, neigh_len, u2e,
                                                  b1, b2, W3, b3, w1p, w2p, out);
    }
}